// Round 1
// baseline (212.401 us; speedup 1.0000x reference)
//
#include <hip/hip_runtime.h>
#include <hip/hip_bf16.h>
#include <math.h>

// out[r][c] = tanh( sum_k 0.25*tanh(kw[k]) * exp(-0.5*((c/L - mean_k)/0.1)^2 - log(0.1*sqrt(2pi))) )
// independent of r and of `values` content -> compute row once, broadcast.
//
// -log(0.1*sqrt(2*pi)) = 1.3836465597...
#define LOG_NORM_NEG 1.3836465597f

__global__ void locate_row_kernel(const float* __restrict__ kw,
                                  float* __restrict__ row, int L) {
    int c = blockIdx.x * blockDim.x + threadIdx.x;
    if (c >= L) return;
    const float means[6] = {0.0f, 0.2f, 0.4f, 0.6f, 0.8f, 1.0f};
    float pos = (float)c / (float)L;
    float s = 0.0f;
#pragma unroll
    for (int k = 0; k < 6; ++k) {
        float w = 0.25f * tanhf(kw[k]);
        float z = (pos - means[k]) * 10.0f;          // / std (0.1)
        float pdf = expf(fmaf(-0.5f * z, z, LOG_NORM_NEG));
        s = fmaf(w, pdf, s);
    }
    row[c] = tanhf(s);
}

// Broadcast row[] across all bs rows using flat float4 stores.
// total (= bs*L) is divisible by 4 and d_out is 16B aligned, so flat vec4
// indexing is always aligned even though L*4 bytes is only 8B aligned.
__global__ void locate_broadcast_kernel(const float* __restrict__ row,
                                        float4* __restrict__ out,
                                        unsigned int L, unsigned int total4) {
    unsigned int i = blockIdx.x * blockDim.x + threadIdx.x;
    if (i >= total4) return;
    unsigned int base = i * 4u;
    unsigned int c = base % L;
    float4 v;
    v.x = row[c]; ++c; if (c == L) c = 0;
    v.y = row[c]; ++c; if (c == L) c = 0;
    v.z = row[c]; ++c; if (c == L) c = 0;
    v.w = row[c];
    out[i] = v;
}

// Fallback if d_ws is too small: compute the 6-kernel sum inline per element.
__global__ void locate_fused_kernel(const float* __restrict__ kw,
                                    float* __restrict__ out,
                                    unsigned int L, unsigned int total) {
    unsigned int i = blockIdx.x * blockDim.x + threadIdx.x;
    if (i >= total) return;
    const float means[6] = {0.0f, 0.2f, 0.4f, 0.6f, 0.8f, 1.0f};
    unsigned int c = i % L;
    float pos = (float)c / (float)L;
    float s = 0.0f;
#pragma unroll
    for (int k = 0; k < 6; ++k) {
        float w = 0.25f * tanhf(kw[k]);
        float z = (pos - means[k]) * 10.0f;
        float pdf = expf(fmaf(-0.5f * z, z, LOG_NORM_NEG));
        s = fmaf(w, pdf, s);
    }
    out[i] = tanhf(s);
}

extern "C" void kernel_launch(void* const* d_in, const int* in_sizes, int n_in,
                              void* d_out, int out_size, void* d_ws, size_t ws_size,
                              hipStream_t stream) {
    const float* kw = (const float*)d_in[1];   // kernel_weights, 6 floats
    float* out = (float*)d_out;

    // Derive shapes: bs*L_in = in_sizes[0], bs*(L_in-2) = out_size
    // => bs = (in_sizes[0] - out_size) / 2
    long long n_values = in_sizes[0];
    long long bs = (n_values - (long long)out_size) / 2;
    int L = (int)((long long)out_size / bs);   // L_in - 2 = 2046

    unsigned int total = (unsigned int)out_size;          // 33,521,664
    if (ws_size >= (size_t)L * sizeof(float)) {
        float* row = (float*)d_ws;
        {
            int threads = 256;
            int blocks = (L + threads - 1) / threads;
            locate_row_kernel<<<blocks, threads, 0, stream>>>(kw, row, L);
        }
        {
            unsigned int total4 = total / 4u;             // 8,380,416
            int threads = 256;
            int blocks = (int)((total4 + threads - 1) / threads);
            locate_broadcast_kernel<<<blocks, threads, 0, stream>>>(
                row, (float4*)out, (unsigned int)L, total4);
        }
    } else {
        int threads = 256;
        int blocks = (int)((total + threads - 1) / threads);
        locate_fused_kernel<<<blocks, threads, 0, stream>>>(
            kw, out, (unsigned int)L, total);
    }
}

// Round 3
// 210.166 us; speedup vs baseline: 1.0106x; 1.0106x over previous
//
#include <hip/hip_runtime.h>
#include <hip/hip_bf16.h>
#include <math.h>

// out[r][c] = tanh( sum_k 0.25*tanh(kw[k]) * exp(-0.5*((c/L - mean_k)/0.1)^2 - log(0.1*sqrt(2pi))) )
// independent of r and of `values` content -> compute row once, broadcast.
// -log(0.1*sqrt(2*pi)) = 1.3836465597...
#define LOG_NORM_NEG 1.3836465597f

typedef float f32x4 __attribute__((ext_vector_type(4)));  // clang vector: valid for nontemporal builtins

__global__ void locate_row_kernel(const float* __restrict__ kw,
                                  float* __restrict__ row, int L) {
    int c = blockIdx.x * blockDim.x + threadIdx.x;
    if (c >= L) return;
    const float means[6] = {0.0f, 0.2f, 0.4f, 0.6f, 0.8f, 1.0f};
    float pos = (float)c / (float)L;
    float s = 0.0f;
#pragma unroll
    for (int k = 0; k < 6; ++k) {
        float w = 0.25f * tanhf(kw[k]);
        float z = (pos - means[k]) * 10.0f;          // / std (0.1)
        float pdf = expf(fmaf(-0.5f * z, z, LOG_NORM_NEG));
        s = fmaf(w, pdf, s);
    }
    row[c] = tanhf(s);
}

// Broadcast: two consecutive rows = 2L floats = nvec f32x4 (16B-aligned since
// 2L % 4 == 0 and pair stride 2L*4 bytes is a multiple of 16).
// Each thread materializes its <=NV pattern vectors ONCE in registers (L2-hit
// gathers), then the hot loop is pure nontemporal 16B stores.
#define NV 4  // pattern vectors per thread: ceil(nvec/256); nvec=1023 -> 4

__global__ __launch_bounds__(256) void locate_broadcast2(
    const float* __restrict__ row, f32x4* __restrict__ out4,
    int L, int pairs, int ppb) {
    const int nvec = (2 * L) / 4;          // 1023 for L=2046
    const int tid  = threadIdx.x;

    f32x4 v[NV];
#pragma unroll
    for (int i = 0; i < NV; ++i) {
        int j = tid + i * 256;
        if (j < nvec) {
            int c = (4 * j) % L;           // one modulo per pattern vector only
            f32x4 t;
            t.x = row[c]; ++c; if (c == L) c = 0;
            t.y = row[c]; ++c; if (c == L) c = 0;
            t.z = row[c]; ++c; if (c == L) c = 0;
            t.w = row[c];
            v[i] = t;
        }
    }

    const int p0 = blockIdx.x * ppb;
    for (int k = 0; k < ppb; ++k) {
        int p = p0 + k;
        if (p >= pairs) return;
        f32x4* dst = out4 + (size_t)p * (size_t)nvec;
#pragma unroll
        for (int i = 0; i < NV; ++i) {
            int j = tid + i * 256;
            if (j < nvec) __builtin_nontemporal_store(v[i], dst + j);
        }
    }
}

// Generic fallback (shapes where NV*256 < nvec or bs odd): per-element gather.
__global__ void locate_fused_kernel(const float* __restrict__ row,
                                    float* __restrict__ out,
                                    unsigned int L, unsigned int total) {
    unsigned int i = blockIdx.x * blockDim.x + threadIdx.x;
    if (i >= total) return;
    out[i] = row[i % L];
}

extern "C" void kernel_launch(void* const* d_in, const int* in_sizes, int n_in,
                              void* d_out, int out_size, void* d_ws, size_t ws_size,
                              hipStream_t stream) {
    const float* kw = (const float*)d_in[1];   // kernel_weights, 6 floats
    float* out = (float*)d_out;

    // bs*L_in = in_sizes[0], bs*(L_in-2) = out_size => bs = (n_values - out)/2
    long long n_values = in_sizes[0];
    long long bs = (n_values - (long long)out_size) / 2;
    int L = (int)((long long)out_size / bs);   // 2046

    float* row = (float*)d_ws;                 // L floats, ws is plenty
    {
        int threads = 256;
        int blocks = (L + threads - 1) / threads;
        locate_row_kernel<<<blocks, threads, 0, stream>>>(kw, row, L);
    }

    bool pair_ok = (bs % 2 == 0) && ((2 * L) % 4 == 0) && ((2 * L) / 4 <= NV * 256);
    if (pair_ok) {
        int pairs = (int)(bs / 2);                       // 8192
        int ppb = (pairs + 1023) / 1024;                 // 8
        int blocks = (pairs + ppb - 1) / ppb;            // 1024
        locate_broadcast2<<<blocks, 256, 0, stream>>>(
            row, (f32x4*)out, L, pairs, ppb);
    } else {
        unsigned int total = (unsigned int)out_size;
        int threads = 256;
        int blocks = (int)((total + threads - 1) / threads);
        locate_fused_kernel<<<blocks, threads, 0, stream>>>(
            row, out, (unsigned int)L, total);
    }
}

// Round 4
// 204.206 us; speedup vs baseline: 1.0401x; 1.0292x over previous
//
#include <hip/hip_runtime.h>
#include <hip/hip_bf16.h>
#include <math.h>

// out[r][c] = tanh( sum_k 0.25*tanh(kw[k]) * exp(-0.5*((c/L - mean_k)/0.1)^2 - log(0.1*sqrt(2pi))) )
// independent of r and of `values` content -> compute row once, broadcast.
// -log(0.1*sqrt(2*pi)) = 1.3836465597...
#define LOG_NORM_NEG 1.3836465597f

typedef float f32x4 __attribute__((ext_vector_type(4)));

__global__ void locate_row_kernel(const float* __restrict__ kw,
                                  float* __restrict__ row, int L) {
    int c = blockIdx.x * blockDim.x + threadIdx.x;
    if (c >= L) return;
    const float means[6] = {0.0f, 0.2f, 0.4f, 0.6f, 0.8f, 1.0f};
    float pos = (float)c / (float)L;
    float s = 0.0f;
#pragma unroll
    for (int k = 0; k < 6; ++k) {
        float w = 0.25f * tanhf(kw[k]);
        float z = (pos - means[k]) * 10.0f;          // / std (0.1)
        float pdf = expf(fmaf(-0.5f * z, z, LOG_NORM_NEG));
        s = fmaf(w, pdf, s);
    }
    row[c] = tanhf(s);
}

// Broadcast: two consecutive rows = 2L floats = nvec f32x4 (16B-aligned since
// 2L % 4 == 0 and pair stride 2L*4 bytes is a multiple of 16).
// Each thread materializes its <=NV pattern vectors ONCE in registers (L2-hit
// gathers), then the hot loop is pure 16B streaming stores.
// R4 change vs R3: regular (cached) stores instead of nontemporal — the
// 128 MiB output fits in Infinity Cache and the 6.7 TB/s fill kernels use the
// cached path; nt forces HBM-direct. Also 4096 blocks (ppb=2) instead of
// 1024 (ppb=8) for more outstanding stores per channel.
#define NV 4  // pattern vectors per thread: ceil(nvec/256); nvec=1023 -> 4

__global__ __launch_bounds__(256) void locate_broadcast2(
    const float* __restrict__ row, f32x4* __restrict__ out4,
    int L, int pairs, int ppb) {
    const int nvec = (2 * L) / 4;          // 1023 for L=2046
    const int tid  = threadIdx.x;

    f32x4 v[NV];
#pragma unroll
    for (int i = 0; i < NV; ++i) {
        int j = tid + i * 256;
        if (j < nvec) {
            int c = (4 * j) % L;           // one modulo per pattern vector only
            f32x4 t;
            t.x = row[c]; ++c; if (c == L) c = 0;
            t.y = row[c]; ++c; if (c == L) c = 0;
            t.z = row[c]; ++c; if (c == L) c = 0;
            t.w = row[c];
            v[i] = t;
        }
    }

    const int p0 = blockIdx.x * ppb;
    for (int k = 0; k < ppb; ++k) {
        int p = p0 + k;
        if (p >= pairs) return;
        f32x4* dst = out4 + (size_t)p * (size_t)nvec;
#pragma unroll
        for (int i = 0; i < NV; ++i) {
            int j = tid + i * 256;
            if (j < nvec) dst[j] = v[i];
        }
    }
}

// Generic fallback (shapes where NV*256 < nvec or bs odd): per-element gather.
__global__ void locate_fused_kernel(const float* __restrict__ row,
                                    float* __restrict__ out,
                                    unsigned int L, unsigned int total) {
    unsigned int i = blockIdx.x * blockDim.x + threadIdx.x;
    if (i >= total) return;
    out[i] = row[i % L];
}

extern "C" void kernel_launch(void* const* d_in, const int* in_sizes, int n_in,
                              void* d_out, int out_size, void* d_ws, size_t ws_size,
                              hipStream_t stream) {
    const float* kw = (const float*)d_in[1];   // kernel_weights, 6 floats
    float* out = (float*)d_out;

    // bs*L_in = in_sizes[0], bs*(L_in-2) = out_size => bs = (n_values - out)/2
    long long n_values = in_sizes[0];
    long long bs = (n_values - (long long)out_size) / 2;
    int L = (int)((long long)out_size / bs);   // 2046

    float* row = (float*)d_ws;                 // L floats, ws is plenty
    {
        int threads = 256;
        int blocks = (L + threads - 1) / threads;
        locate_row_kernel<<<blocks, threads, 0, stream>>>(kw, row, L);
    }

    bool pair_ok = (bs % 2 == 0) && ((2 * L) % 4 == 0) && ((2 * L) / 4 <= NV * 256);
    if (pair_ok) {
        int pairs = (int)(bs / 2);                       // 8192
        int ppb = 2;                                     // -> 4096 blocks
        int blocks = (pairs + ppb - 1) / ppb;
        locate_broadcast2<<<blocks, 256, 0, stream>>>(
            row, (f32x4*)out, L, pairs, ppb);
    } else {
        unsigned int total = (unsigned int)out_size;
        int threads = 256;
        int blocks = (int)((total + threads - 1) / threads);
        locate_fused_kernel<<<blocks, threads, 0, stream>>>(
            row, out, (unsigned int)L, total);
    }
}